// Round 1
// baseline (1755.716 us; speedup 1.0000x reference)
//
#include <hip/hip_runtime.h>
#include <stdint.h>

// ---------------------------------------------------------------------------
// TContrastive: GRACE InfoNCE loss.
//   loss_view = (1/2N) sum_i log(S_i - e^2) - (2/N) sum_i g12_i
// where S = row sums of exp(2 * M M^T), M = [n1; n2] row-normalized (16384x1024).
// All heavy GEMMs in bf16 MFMA (16x16x32), fp32 accumulate. tau = 0.5.
// ---------------------------------------------------------------------------

typedef unsigned short u16;
typedef __attribute__((ext_vector_type(8))) __bf16 bf16x8;
typedef __attribute__((ext_vector_type(4))) float f32x4;

#define NS 8192       // samples per view half
#define DD 1024       // feature dim

__device__ __forceinline__ float bf2f(u16 u) {
    union { uint32_t i; float f; } v; v.i = ((uint32_t)u) << 16; return v.f;
}
__device__ __forceinline__ u16 f2bf(float f) {
    union { float f; uint32_t i; } v; v.f = f;
    return (u16)((v.i + 0x7FFFu + ((v.i >> 16) & 1u)) >> 16);   // RNE
}

// async global->LDS, 16B per lane. LDS dest must be wave-uniform-base + lane*16.
__device__ __forceinline__ void gload16(const u16* g, u16* l) {
    __builtin_amdgcn_global_load_lds(
        (__attribute__((address_space(1))) void*)(uintptr_t)(g),
        (__attribute__((address_space(3))) void*)(uintptr_t)(l), 16, 0, 0);
}

// ---------------- elementwise conversion kernels ----------------

// fp32 -> bf16, 4 elems/thread (for weight matrices, 1M elems -> 1024 blocks)
__global__ __launch_bounds__(256) void conv_f2bf(const float* __restrict__ src,
                                                 u16* __restrict__ dst) {
    int i = (blockIdx.x * 256 + threadIdx.x) * 4;
    float4 v = *(const float4*)(src + i);
    ushort4 o;
    o.x = f2bf(v.x); o.y = f2bf(v.y); o.z = f2bf(v.z); o.w = f2bf(v.w);
    *(ushort4*)(dst + i) = o;
}

// Z = bf16([ta; tb]) row view (16384x1024), 16384 blocks
__global__ __launch_bounds__(256) void conv_cat(const float* __restrict__ a,
                                                const float* __restrict__ b,
                                                u16* __restrict__ Z) {
    size_t i = (size_t)(blockIdx.x * 256 + threadIdx.x) * 4;
    const size_t half = (size_t)NS * DD;
    const float* s = (i < half) ? (a + i) : (b + (i - half));
    float4 v = *(const float4*)s;
    ushort4 o;
    o.x = f2bf(v.x); o.y = f2bf(v.y); o.z = f2bf(v.z); o.w = f2bf(v.w);
    *(ushort4*)(Z + i) = o;
}

// column view: Z[i, b*32+a] = src[i, a*32+b]  (per-row 32x32 transpose)
__global__ __launch_bounds__(256) void conv_col(const float* __restrict__ a,
                                                const float* __restrict__ b,
                                                u16* __restrict__ Z) {
    size_t i = (size_t)(blockIdx.x * 256 + threadIdx.x) * 4;
    const size_t half = (size_t)NS * DD;
    const float* src; size_t o;
    if (i < half) { src = a; o = i; } else { src = b; o = i - half; }
    size_t row = o >> 10;
    int j = (int)(o & 1023);
    int aI = j & 31, bI = j >> 5;      // j = b*32 + a
    const float* rp = src + (row << 10);
    ushort4 ov;
    ov.x = f2bf(rp[aI * 32 + bI]);
    ov.y = f2bf(rp[(aI + 1) * 32 + bI]);
    ov.z = f2bf(rp[(aI + 2) * 32 + bI]);
    ov.w = f2bf(rp[(aI + 3) * 32 + bI]);
    *(ushort4*)(Z + i) = ov;
}

// ---------------- GEMM: C[m,n] = sum_k A[m,k] * B[n,k]  (A: Mx1024, B: Nx1024)
// MODE 0: out = bf16(elu(C + bias))      (fc_a)
// MODE 1: out = bf16(C + bias)           (fc_b)
// MODE 2: S[m] += sum_n exp(2*C[m,n])    (Gram row sums; A == B == normalized M)
template <int MODE>
__global__ __launch_bounds__(256) void gemm_bt(const u16* A, const u16* B,
                                               const float* __restrict__ bias,
                                               u16* __restrict__ out,
                                               float* __restrict__ S) {
    __shared__ alignas(16) u16 As[128 * 32];
    __shared__ alignas(16) u16 Bs[128 * 32];
    const int tid = threadIdx.x;

    int tm, tn;
    if (MODE == 2) {
        // supertile swizzle: 16 consecutive tileM rows per sweep for L2/L3 locality
        int flat = blockIdx.y * 128 + blockIdx.x;
        int grp = flat >> 11;          // / (128*16)
        int rem = flat & 2047;
        tm = (grp << 4) | (rem & 15);
        tn = rem >> 4;
    } else {
        tm = blockIdx.y; tn = blockIdx.x;
    }
    const size_t tileM = (size_t)tm * 128;
    const size_t tileN = (size_t)tn * 128;

    // staging: chunk c in [0,512), 16B each; row = c>>2, kcol = (c&3)*8
    const u16* gA0 = A + (tileM + (tid >> 2)) * DD + (tid & 3) * 8;
    const u16* gA1 = gA0 + (size_t)64 * DD;
    const u16* gB0 = B + (tileN + (tid >> 2)) * DD + (tid & 3) * 8;
    const u16* gB1 = gB0 + (size_t)64 * DD;
    u16* lA0 = &As[tid * 8]; u16* lA1 = lA0 + 2048;
    u16* lB0 = &Bs[tid * 8]; u16* lB1 = lB0 + 2048;

    const int lane = tid & 63;
    const int wv = tid >> 6;
    const int wr = (wv >> 1) << 6;     // wave row quadrant
    const int wc = (wv & 1) << 6;      // wave col quadrant
    const int lr = lane & 15;          // A/B operand: m/n index; C: col
    const int lh = lane >> 4;          // A/B operand: k-group; C: row-group

    const u16* aBase = &As[(wr + lr) * 32 + lh * 8];
    const u16* bBase = &Bs[(wc + lr) * 32 + lh * 8];

    f32x4 acc[4][4];
#pragma unroll
    for (int i = 0; i < 4; i++)
#pragma unroll
        for (int j = 0; j < 4; j++) acc[i][j] = (f32x4)0.0f;

    for (int k0 = 0; k0 < DD; k0 += 32) {
        gload16(gA0 + k0, lA0);
        gload16(gA1 + k0, lA1);
        gload16(gB0 + k0, lB0);
        gload16(gB1 + k0, lB1);
        __syncthreads();
        bf16x8 af[4], bfr[4];
#pragma unroll
        for (int rt = 0; rt < 4; rt++) af[rt] = *(const bf16x8*)(aBase + rt * 512);
#pragma unroll
        for (int ct = 0; ct < 4; ct++) bfr[ct] = *(const bf16x8*)(bBase + ct * 512);
#pragma unroll
        for (int rt = 0; rt < 4; rt++)
#pragma unroll
            for (int ct = 0; ct < 4; ct++)
                acc[rt][ct] = __builtin_amdgcn_mfma_f32_16x16x32_bf16(
                    af[rt], bfr[ct], acc[rt][ct], 0, 0, 0);
        __syncthreads();
    }

    if (MODE <= 1) {
        float bcol[4];
#pragma unroll
        for (int ct = 0; ct < 4; ct++) bcol[ct] = bias[tileN + wc + ct * 16 + lr];
#pragma unroll
        for (int rt = 0; rt < 4; rt++) {
#pragma unroll
            for (int r = 0; r < 4; r++) {
                size_t row = tileM + wr + rt * 16 + lh * 4 + r;
                u16* orow = out + row * DD + tileN + wc + lr;
#pragma unroll
                for (int ct = 0; ct < 4; ct++) {
                    float v = acc[rt][ct][r] + bcol[ct];
                    if (MODE == 0) v = v > 0.0f ? v : expm1f(v);
                    orow[ct * 16] = f2bf(v);
                }
            }
        }
    } else {
#pragma unroll
        for (int rt = 0; rt < 4; rt++) {
#pragma unroll
            for (int r = 0; r < 4; r++) {
                float s = 0.0f;
#pragma unroll
                for (int ct = 0; ct < 4; ct++) s += __expf(2.0f * acc[rt][ct][r]);
                // reduce across the 16 lanes holding the 16 cols of this row
                s += __shfl_xor(s, 1);
                s += __shfl_xor(s, 2);
                s += __shfl_xor(s, 4);
                s += __shfl_xor(s, 8);
                if (lr == 0) {
                    size_t row = tileM + wr + rt * 16 + lh * 4 + r;
                    atomicAdd(&S[row], s);
                }
            }
        }
    }
}

// row-normalize bf16 matrix in place (one block per row of 1024)
__global__ __launch_bounds__(256) void normalize_kernel(u16* M) {
    __shared__ float red[4];
    const int tid = threadIdx.x;
    u16* row = M + ((size_t)blockIdx.x << 10);
    ushort4 v = ((const ushort4*)row)[tid];
    float x0 = bf2f(v.x), x1 = bf2f(v.y), x2 = bf2f(v.z), x3 = bf2f(v.w);
    float s = x0 * x0 + x1 * x1 + x2 * x2 + x3 * x3;
#pragma unroll
    for (int m = 1; m < 64; m <<= 1) s += __shfl_xor(s, m);
    if ((tid & 63) == 0) red[tid >> 6] = s;
    __syncthreads();
    float inv = rsqrtf(red[0] + red[1] + red[2] + red[3]);
    ushort4 o;
    o.x = f2bf(x0 * inv); o.y = f2bf(x1 * inv);
    o.z = f2bf(x2 * inv); o.w = f2bf(x3 * inv);
    ((ushort4*)row)[tid] = o;
}

// g12[i] = dot(M[i], M[i+NS])  (one block per i)
__global__ __launch_bounds__(256) void diag_kernel(const u16* M, float* g12) {
    __shared__ float red[4];
    const int tid = threadIdx.x;
    const u16* r1 = M + ((size_t)blockIdx.x << 10);
    const u16* r2 = r1 + ((size_t)NS << 10);
    ushort4 a = ((const ushort4*)r1)[tid];
    ushort4 b = ((const ushort4*)r2)[tid];
    float s = bf2f(a.x) * bf2f(b.x) + bf2f(a.y) * bf2f(b.y) +
              bf2f(a.z) * bf2f(b.z) + bf2f(a.w) * bf2f(b.w);
#pragma unroll
    for (int m = 1; m < 64; m <<= 1) s += __shfl_xor(s, m);
    if ((tid & 63) == 0) red[tid >> 6] = s;
    __syncthreads();
    if (tid == 0) g12[blockIdx.x] = red[0] + red[1] + red[2] + red[3];
}

__global__ __launch_bounds__(256) void final_kernel(const float* Sr, const float* Sc,
                                                    const float* gr, const float* gc,
                                                    const float* w_r1, float* out) {
    __shared__ float red[16];
    const float E2 = 7.389056098930650f;  // exp(1/tau), tau=0.5
    float a = 0.f, b = 0.f, c = 0.f, d = 0.f;
    for (int i = threadIdx.x; i < 2 * NS; i += 256) {
        a += logf(Sr[i] - E2);
        b += logf(Sc[i] - E2);
    }
    for (int i = threadIdx.x; i < NS; i += 256) {
        c += gr[i];
        d += gc[i];
    }
#pragma unroll
    for (int m = 1; m < 64; m <<= 1) {
        a += __shfl_xor(a, m); b += __shfl_xor(b, m);
        c += __shfl_xor(c, m); d += __shfl_xor(d, m);
    }
    int w = threadIdx.x >> 6;
    if ((threadIdx.x & 63) == 0) {
        red[w] = a; red[4 + w] = b; red[8 + w] = c; red[12 + w] = d;
    }
    __syncthreads();
    if (threadIdx.x == 0) {
        a = red[0] + red[1] + red[2] + red[3];
        b = red[4] + red[5] + red[6] + red[7];
        c = red[8] + red[9] + red[10] + red[11];
        d = red[12] + red[13] + red[14] + red[15];
        float lr = a / (2.0f * NS) - 2.0f * c / NS;
        float lc = b / (2.0f * NS) - 2.0f * d / NS;
        float w0 = w_r1[0];
        w0 = fminf(fmaxf(w0, 0.0f), 1.0f);
        out[0] = w0 * lr + (1.0f - w0) * lc;
    }
}

extern "C" void kernel_launch(void* const* d_in, const int* in_sizes, int n_in,
                              void* d_out, int out_size, void* d_ws, size_t ws_size,
                              hipStream_t stream) {
    const float* ta = (const float*)d_in[0];
    const float* tb = (const float*)d_in[1];
    const float* W1 = (const float*)d_in[2];
    const float* b1 = (const float*)d_in[3];
    const float* W2 = (const float*)d_in[4];
    const float* b2 = (const float*)d_in[5];
    const float* W3 = (const float*)d_in[6];
    const float* b3 = (const float*)d_in[7];
    const float* W4 = (const float*)d_in[8];
    const float* b4 = (const float*)d_in[9];
    const float* wr = (const float*)d_in[10];
    float* out = (float*)d_out;

    char* p = (char*)d_ws;
    const size_t MAT = (size_t)2 * NS * DD * sizeof(u16);  // 33.5 MB
    u16* Z = (u16*)p;  p += MAT;
    u16* T = (u16*)p;  p += MAT;
    u16* H = (u16*)p;  p += MAT;
    u16* Wb = (u16*)p; p += (size_t)4 * DD * DD * sizeof(u16);
    float* Sr = (float*)p;  p += 2 * NS * sizeof(float);
    float* Sc = (float*)p;  p += 2 * NS * sizeof(float);
    float* gr = (float*)p;  p += NS * sizeof(float);
    float* gc = (float*)p;  p += NS * sizeof(float);

    u16* Wb1 = Wb;
    u16* Wb2 = Wb + (size_t)DD * DD;
    u16* Wb3 = Wb + (size_t)2 * DD * DD;
    u16* Wb4 = Wb + (size_t)3 * DD * DD;

    conv_f2bf<<<1024, 256, 0, stream>>>(W1, Wb1);
    conv_f2bf<<<1024, 256, 0, stream>>>(W2, Wb2);
    conv_f2bf<<<1024, 256, 0, stream>>>(W3, Wb3);
    conv_f2bf<<<1024, 256, 0, stream>>>(W4, Wb4);
    hipMemsetAsync(Sr, 0, 4 * NS * sizeof(float), stream);  // Sr and Sc contiguous

    // ---- row view ----
    conv_cat<<<16384, 256, 0, stream>>>(ta, tb, Z);
    gemm_bt<0><<<dim3(8, 128), 256, 0, stream>>>(Z, Wb1, b1, T, nullptr);
    gemm_bt<1><<<dim3(8, 128), 256, 0, stream>>>(T, Wb2, b2, H, nullptr);
    normalize_kernel<<<16384, 256, 0, stream>>>(H);
    diag_kernel<<<8192, 256, 0, stream>>>(H, gr);
    gemm_bt<2><<<dim3(128, 128), 256, 0, stream>>>(H, H, nullptr, nullptr, Sr);

    // ---- column view ----
    conv_col<<<16384, 256, 0, stream>>>(ta, tb, Z);
    gemm_bt<0><<<dim3(8, 128), 256, 0, stream>>>(Z, Wb3, b3, T, nullptr);
    gemm_bt<1><<<dim3(8, 128), 256, 0, stream>>>(T, Wb4, b4, H, nullptr);
    normalize_kernel<<<16384, 256, 0, stream>>>(H);
    diag_kernel<<<8192, 256, 0, stream>>>(H, gc);
    gemm_bt<2><<<dim3(128, 128), 256, 0, stream>>>(H, H, nullptr, nullptr, Sc);

    final_kernel<<<1, 256, 0, stream>>>(Sr, Sc, gr, gc, wr, out);
}

// Round 2
// 1224.227 us; speedup vs baseline: 1.4341x; 1.4341x over previous
//
#include <hip/hip_runtime.h>
#include <stdint.h>

// ---------------------------------------------------------------------------
// TContrastive: GRACE InfoNCE loss.
//   loss_view = (1/2N) sum_i log(S_i - e^2) - (2/N) sum_i g12_i
// where S = row sums of exp(2 * M M^T), M = [n1; n2] row-normalized (16384x1024).
// All heavy GEMMs in bf16 MFMA (16x16x32), fp32 accumulate. tau = 0.5.
// R1: exploit Gram symmetry — compute only tile triangle i<=j; off-diag tiles
//     contribute exp-row-sums to S[rows_i] and exp-col-sums to S[rows_j].
// ---------------------------------------------------------------------------

typedef unsigned short u16;
typedef __attribute__((ext_vector_type(8))) __bf16 bf16x8;
typedef __attribute__((ext_vector_type(4))) float f32x4;

#define NS 8192       // samples per view half
#define DD 1024       // feature dim

__device__ __forceinline__ float bf2f(u16 u) {
    union { uint32_t i; float f; } v; v.i = ((uint32_t)u) << 16; return v.f;
}
__device__ __forceinline__ u16 f2bf(float f) {
    union { float f; uint32_t i; } v; v.f = f;
    return (u16)((v.i + 0x7FFFu + ((v.i >> 16) & 1u)) >> 16);   // RNE
}

// async global->LDS, 16B per lane. LDS dest must be wave-uniform-base + lane*16.
__device__ __forceinline__ void gload16(const u16* g, u16* l) {
    __builtin_amdgcn_global_load_lds(
        (__attribute__((address_space(1))) void*)(uintptr_t)(g),
        (__attribute__((address_space(3))) void*)(uintptr_t)(l), 16, 0, 0);
}

// ---------------- elementwise conversion kernels ----------------

__global__ __launch_bounds__(256) void conv_f2bf(const float* __restrict__ src,
                                                 u16* __restrict__ dst) {
    int i = (blockIdx.x * 256 + threadIdx.x) * 4;
    float4 v = *(const float4*)(src + i);
    ushort4 o;
    o.x = f2bf(v.x); o.y = f2bf(v.y); o.z = f2bf(v.z); o.w = f2bf(v.w);
    *(ushort4*)(dst + i) = o;
}

// Z = bf16([ta; tb]) row view (16384x1024), 16384 blocks
__global__ __launch_bounds__(256) void conv_cat(const float* __restrict__ a,
                                                const float* __restrict__ b,
                                                u16* __restrict__ Z) {
    size_t i = (size_t)(blockIdx.x * 256 + threadIdx.x) * 4;
    const size_t half = (size_t)NS * DD;
    const float* s = (i < half) ? (a + i) : (b + (i - half));
    float4 v = *(const float4*)s;
    ushort4 o;
    o.x = f2bf(v.x); o.y = f2bf(v.y); o.z = f2bf(v.z); o.w = f2bf(v.w);
    *(ushort4*)(Z + i) = o;
}

// column view: Z[i, b*32+a] = src[i, a*32+b]  (per-row 32x32 transpose)
__global__ __launch_bounds__(256) void conv_col(const float* __restrict__ a,
                                                const float* __restrict__ b,
                                                u16* __restrict__ Z) {
    size_t i = (size_t)(blockIdx.x * 256 + threadIdx.x) * 4;
    const size_t half = (size_t)NS * DD;
    const float* src; size_t o;
    if (i < half) { src = a; o = i; } else { src = b; o = i - half; }
    size_t row = o >> 10;
    int j = (int)(o & 1023);
    int aI = j & 31, bI = j >> 5;      // j = b*32 + a
    const float* rp = src + (row << 10);
    ushort4 ov;
    ov.x = f2bf(rp[aI * 32 + bI]);
    ov.y = f2bf(rp[(aI + 1) * 32 + bI]);
    ov.z = f2bf(rp[(aI + 2) * 32 + bI]);
    ov.w = f2bf(rp[(aI + 3) * 32 + bI]);
    *(ushort4*)(Z + i) = ov;
}

// ---------------- GEMM: C[m,n] = sum_k A[m,k] * B[n,k]  (A: Mx1024, B: Nx1024)
// MODE 0: out = bf16(elu(C + bias))      (fc_a)
// MODE 1: out = bf16(C + bias)           (fc_b)
// MODE 2: triangular Gram: S[row] += exp-row-sums, and for off-diag tiles
//         S[col] += exp-col-sums (symmetry). Grid dim3(129, 64).
template <int MODE>
__global__ __launch_bounds__(256) void gemm_bt(const u16* A, const u16* B,
                                               const float* __restrict__ bias,
                                               u16* __restrict__ out,
                                               float* __restrict__ S) {
    __shared__ alignas(16) u16 As[128 * 32];
    __shared__ alignas(16) u16 Bs[128 * 32];
    const int tid = threadIdx.x;

    int tm, tn;
    if (MODE == 2) {
        // triangle decode: covers each (i<=j) tile pair exactly once
        int x = blockIdx.x, y = blockIdx.y;      // x in [0,129), y in [0,64)
        if (y + x < 128) { tm = y;       tn = y + x; }
        else             { tm = 127 - y; tn = x - 1; }
    } else {
        tm = blockIdx.y; tn = blockIdx.x;
    }
    const size_t tileM = (size_t)tm * 128;
    const size_t tileN = (size_t)tn * 128;

    // staging: chunk c in [0,512), 16B each; row = c>>2, kcol = (c&3)*8
    const u16* gA0 = A + (tileM + (tid >> 2)) * DD + (tid & 3) * 8;
    const u16* gA1 = gA0 + (size_t)64 * DD;
    const u16* gB0 = B + (tileN + (tid >> 2)) * DD + (tid & 3) * 8;
    const u16* gB1 = gB0 + (size_t)64 * DD;
    u16* lA0 = &As[tid * 8]; u16* lA1 = lA0 + 2048;
    u16* lB0 = &Bs[tid * 8]; u16* lB1 = lB0 + 2048;

    const int lane = tid & 63;
    const int wv = tid >> 6;
    const int wr = (wv >> 1) << 6;     // wave row quadrant
    const int wc = (wv & 1) << 6;      // wave col quadrant
    const int lr = lane & 15;          // A/B operand: m/n index; C: col
    const int lh = lane >> 4;          // A/B operand: k-group; C: row-group

    const u16* aBase = &As[(wr + lr) * 32 + lh * 8];
    const u16* bBase = &Bs[(wc + lr) * 32 + lh * 8];

    f32x4 acc[4][4];
#pragma unroll
    for (int i = 0; i < 4; i++)
#pragma unroll
        for (int j = 0; j < 4; j++) acc[i][j] = (f32x4)0.0f;

    for (int k0 = 0; k0 < DD; k0 += 32) {
        gload16(gA0 + k0, lA0);
        gload16(gA1 + k0, lA1);
        gload16(gB0 + k0, lB0);
        gload16(gB1 + k0, lB1);
        __syncthreads();
        bf16x8 af[4], bfr[4];
#pragma unroll
        for (int rt = 0; rt < 4; rt++) af[rt] = *(const bf16x8*)(aBase + rt * 512);
#pragma unroll
        for (int ct = 0; ct < 4; ct++) bfr[ct] = *(const bf16x8*)(bBase + ct * 512);
#pragma unroll
        for (int rt = 0; rt < 4; rt++)
#pragma unroll
            for (int ct = 0; ct < 4; ct++)
                acc[rt][ct] = __builtin_amdgcn_mfma_f32_16x16x32_bf16(
                    af[rt], bfr[ct], acc[rt][ct], 0, 0, 0);
        __syncthreads();
    }

    if (MODE <= 1) {
        float bcol[4];
#pragma unroll
        for (int ct = 0; ct < 4; ct++) bcol[ct] = bias[tileN + wc + ct * 16 + lr];
#pragma unroll
        for (int rt = 0; rt < 4; rt++) {
#pragma unroll
            for (int r = 0; r < 4; r++) {
                size_t row = tileM + wr + rt * 16 + lh * 4 + r;
                u16* orow = out + row * DD + tileN + wc + lr;
#pragma unroll
                for (int ct = 0; ct < 4; ct++) {
                    float v = acc[rt][ct][r] + bcol[ct];
                    if (MODE == 0) v = v > 0.0f ? v : expm1f(v);
                    orow[ct * 16] = f2bf(v);
                }
            }
        }
    } else {
        const bool offdiag = (tm != tn);
        float colsum[4] = {0.f, 0.f, 0.f, 0.f};
#pragma unroll
        for (int rt = 0; rt < 4; rt++) {
#pragma unroll
            for (int r = 0; r < 4; r++) {
                float rs = 0.0f;
#pragma unroll
                for (int ct = 0; ct < 4; ct++) {
                    float e = __expf(2.0f * acc[rt][ct][r]);
                    rs += e;
                    colsum[ct] += e;
                }
                // reduce across the 16 lanes (lr) holding this row's cols
                rs += __shfl_xor(rs, 1);
                rs += __shfl_xor(rs, 2);
                rs += __shfl_xor(rs, 4);
                rs += __shfl_xor(rs, 8);
                if (lr == 0) {
                    size_t row = tileM + wr + rt * 16 + lh * 4 + r;
                    atomicAdd(&S[row], rs);
                }
            }
        }
        if (offdiag) {
            // col c = tileN + wc + ct*16 + lr; reduce across lh (lanes ^16, ^32)
#pragma unroll
            for (int ct = 0; ct < 4; ct++) {
                float cs = colsum[ct];
                cs += __shfl_xor(cs, 16);
                cs += __shfl_xor(cs, 32);
                if (lh == 0) {
                    size_t col = tileN + wc + ct * 16 + lr;
                    atomicAdd(&S[col], cs);
                }
            }
        }
    }
}

// row-normalize bf16 matrix in place (one block per row of 1024)
__global__ __launch_bounds__(256) void normalize_kernel(u16* M) {
    __shared__ float red[4];
    const int tid = threadIdx.x;
    u16* row = M + ((size_t)blockIdx.x << 10);
    ushort4 v = ((const ushort4*)row)[tid];
    float x0 = bf2f(v.x), x1 = bf2f(v.y), x2 = bf2f(v.z), x3 = bf2f(v.w);
    float s = x0 * x0 + x1 * x1 + x2 * x2 + x3 * x3;
#pragma unroll
    for (int m = 1; m < 64; m <<= 1) s += __shfl_xor(s, m);
    if ((tid & 63) == 0) red[tid >> 6] = s;
    __syncthreads();
    float inv = rsqrtf(red[0] + red[1] + red[2] + red[3]);
    ushort4 o;
    o.x = f2bf(x0 * inv); o.y = f2bf(x1 * inv);
    o.z = f2bf(x2 * inv); o.w = f2bf(x3 * inv);
    ((ushort4*)row)[tid] = o;
}

// g12[i] = dot(M[i], M[i+NS])  (one block per i)
__global__ __launch_bounds__(256) void diag_kernel(const u16* M, float* g12) {
    __shared__ float red[4];
    const int tid = threadIdx.x;
    const u16* r1 = M + ((size_t)blockIdx.x << 10);
    const u16* r2 = r1 + ((size_t)NS << 10);
    ushort4 a = ((const ushort4*)r1)[tid];
    ushort4 b = ((const ushort4*)r2)[tid];
    float s = bf2f(a.x) * bf2f(b.x) + bf2f(a.y) * bf2f(b.y) +
              bf2f(a.z) * bf2f(b.z) + bf2f(a.w) * bf2f(b.w);
#pragma unroll
    for (int m = 1; m < 64; m <<= 1) s += __shfl_xor(s, m);
    if ((tid & 63) == 0) red[tid >> 6] = s;
    __syncthreads();
    if (tid == 0) g12[blockIdx.x] = red[0] + red[1] + red[2] + red[3];
}

__global__ __launch_bounds__(256) void final_kernel(const float* Sr, const float* Sc,
                                                    const float* gr, const float* gc,
                                                    const float* w_r1, float* out) {
    __shared__ float red[16];
    const float E2 = 7.389056098930650f;  // exp(1/tau), tau=0.5
    float a = 0.f, b = 0.f, c = 0.f, d = 0.f;
    for (int i = threadIdx.x; i < 2 * NS; i += 256) {
        a += logf(Sr[i] - E2);
        b += logf(Sc[i] - E2);
    }
    for (int i = threadIdx.x; i < NS; i += 256) {
        c += gr[i];
        d += gc[i];
    }
#pragma unroll
    for (int m = 1; m < 64; m <<= 1) {
        a += __shfl_xor(a, m); b += __shfl_xor(b, m);
        c += __shfl_xor(c, m); d += __shfl_xor(d, m);
    }
    int w = threadIdx.x >> 6;
    if ((threadIdx.x & 63) == 0) {
        red[w] = a; red[4 + w] = b; red[8 + w] = c; red[12 + w] = d;
    }
    __syncthreads();
    if (threadIdx.x == 0) {
        a = red[0] + red[1] + red[2] + red[3];
        b = red[4] + red[5] + red[6] + red[7];
        c = red[8] + red[9] + red[10] + red[11];
        d = red[12] + red[13] + red[14] + red[15];
        float lr = a / (2.0f * NS) - 2.0f * c / NS;
        float lc = b / (2.0f * NS) - 2.0f * d / NS;
        float w0 = w_r1[0];
        w0 = fminf(fmaxf(w0, 0.0f), 1.0f);
        out[0] = w0 * lr + (1.0f - w0) * lc;
    }
}

extern "C" void kernel_launch(void* const* d_in, const int* in_sizes, int n_in,
                              void* d_out, int out_size, void* d_ws, size_t ws_size,
                              hipStream_t stream) {
    const float* ta = (const float*)d_in[0];
    const float* tb = (const float*)d_in[1];
    const float* W1 = (const float*)d_in[2];
    const float* b1 = (const float*)d_in[3];
    const float* W2 = (const float*)d_in[4];
    const float* b2 = (const float*)d_in[5];
    const float* W3 = (const float*)d_in[6];
    const float* b3 = (const float*)d_in[7];
    const float* W4 = (const float*)d_in[8];
    const float* b4 = (const float*)d_in[9];
    const float* wr = (const float*)d_in[10];
    float* out = (float*)d_out;

    char* p = (char*)d_ws;
    const size_t MAT = (size_t)2 * NS * DD * sizeof(u16);  // 33.5 MB
    u16* Z = (u16*)p;  p += MAT;
    u16* T = (u16*)p;  p += MAT;
    u16* H = (u16*)p;  p += MAT;
    u16* Wb = (u16*)p; p += (size_t)4 * DD * DD * sizeof(u16);
    float* Sr = (float*)p;  p += 2 * NS * sizeof(float);
    float* Sc = (float*)p;  p += 2 * NS * sizeof(float);
    float* gr = (float*)p;  p += NS * sizeof(float);
    float* gc = (float*)p;  p += NS * sizeof(float);

    u16* Wb1 = Wb;
    u16* Wb2 = Wb + (size_t)DD * DD;
    u16* Wb3 = Wb + (size_t)2 * DD * DD;
    u16* Wb4 = Wb + (size_t)3 * DD * DD;

    conv_f2bf<<<1024, 256, 0, stream>>>(W1, Wb1);
    conv_f2bf<<<1024, 256, 0, stream>>>(W2, Wb2);
    conv_f2bf<<<1024, 256, 0, stream>>>(W3, Wb3);
    conv_f2bf<<<1024, 256, 0, stream>>>(W4, Wb4);
    hipMemsetAsync(Sr, 0, 4 * NS * sizeof(float), stream);  // Sr and Sc contiguous

    // ---- row view ----
    conv_cat<<<16384, 256, 0, stream>>>(ta, tb, Z);
    gemm_bt<0><<<dim3(8, 128), 256, 0, stream>>>(Z, Wb1, b1, T, nullptr);
    gemm_bt<1><<<dim3(8, 128), 256, 0, stream>>>(T, Wb2, b2, H, nullptr);
    normalize_kernel<<<16384, 256, 0, stream>>>(H);
    diag_kernel<<<8192, 256, 0, stream>>>(H, gr);
    gemm_bt<2><<<dim3(129, 64), 256, 0, stream>>>(H, H, nullptr, nullptr, Sr);

    // ---- column view ----
    conv_col<<<16384, 256, 0, stream>>>(ta, tb, Z);
    gemm_bt<0><<<dim3(8, 128), 256, 0, stream>>>(Z, Wb3, b3, T, nullptr);
    gemm_bt<1><<<dim3(8, 128), 256, 0, stream>>>(T, Wb4, b4, H, nullptr);
    normalize_kernel<<<16384, 256, 0, stream>>>(H);
    diag_kernel<<<8192, 256, 0, stream>>>(H, gc);
    gemm_bt<2><<<dim3(129, 64), 256, 0, stream>>>(H, H, nullptr, nullptr, Sc);

    final_kernel<<<1, 256, 0, stream>>>(Sr, Sc, gr, gc, wr, out);
}